// Round 1
// baseline (1520.191 us; speedup 1.0000x reference)
//
#include <hip/hip_runtime.h>

#define F_IN  128
#define F_HID 64
#define F_OUT 40

// ---------------- degree ----------------
__global__ void k_init_deg(float* __restrict__ deg, int n) {
    int i = blockIdx.x * blockDim.x + threadIdx.x;
    if (i < n) deg[i] = 1.0f;  // self-loop
}

__global__ void k_count_deg(const int* __restrict__ col, int E, float* __restrict__ deg) {
    int i = blockIdx.x * blockDim.x + threadIdx.x;
    int stride = gridDim.x * blockDim.x;
    for (int e = i; e < E; e += stride)
        atomicAdd(&deg[col[e]], 1.0f);
}

__global__ void k_dinv(float* __restrict__ deg, int n) {
    int i = blockIdx.x * blockDim.x + threadIdx.x;
    if (i < n) deg[i] = rsqrtf(deg[i]);
}

// ---------------- layer 1 linear: h1s = dinv * (x @ W1); agg1 = h1s ----------------
// block = 256 threads, 8 nodes per block. W1 (128x64) staged in LDS (32KB).
__global__ void k_lin1(const float* __restrict__ x, const float* __restrict__ W1,
                       const float* __restrict__ dinv,
                       float* __restrict__ h1s, float* __restrict__ agg1, int n) {
    __shared__ float Ws[F_IN * F_HID];   // 32 KB
    __shared__ float xs[8][F_IN];        // 4 KB
    int t = threadIdx.x;
    for (int i = t; i < F_IN * F_HID; i += 256) Ws[i] = W1[i];
    int node0 = blockIdx.x * 8;
    for (int i = t; i < 8 * F_IN; i += 256) {
        int nd = node0 + (i >> 7);
        xs[i >> 7][i & 127] = (nd < n) ? x[nd * F_IN + (i & 127)] : 0.f;
    }
    __syncthreads();
    int local = t >> 5;       // node within block, 0..7
    int j0 = t & 31;          // output col 0..31 (also handles j0+32)
    float acc0 = 0.f, acc1 = 0.f;
#pragma unroll 8
    for (int k = 0; k < F_IN; ++k) {
        float xv = xs[local][k];
        acc0 = fmaf(xv, Ws[k * F_HID + j0], acc0);
        acc1 = fmaf(xv, Ws[k * F_HID + j0 + 32], acc1);
    }
    int nd = node0 + local;
    if (nd < n) {
        float s = dinv[nd];
        float v0 = acc0 * s, v1 = acc1 * s;
        h1s[nd * F_HID + j0]       = v0;
        h1s[nd * F_HID + j0 + 32]  = v1;
        agg1[nd * F_HID + j0]      = v0;   // self-loop pre-seeded
        agg1[nd * F_HID + j0 + 32] = v1;
    }
}

// ---------------- edge aggregation, 64 features: agg[col] += h[row] ----------------
__global__ void k_agg64(const int* __restrict__ row, const int* __restrict__ col,
                        const float* __restrict__ h, float* __restrict__ agg, int E) {
    int gtid = blockIdx.x * blockDim.x + threadIdx.x;
    int wid = gtid >> 6;
    int lane = threadIdx.x & 63;
    int nwaves = (gridDim.x * blockDim.x) >> 6;
    for (int e = wid; e < E; e += nwaves) {
        int r = row[e];
        int c = col[e];
        float v = h[r * F_HID + lane];
        atomicAdd(&agg[c * F_HID + lane], v);
    }
}

// ---------------- z1 = relu(dinv[c]*agg1 + b1), in place ----------------
__global__ void k_bias_relu(float* __restrict__ agg, const float* __restrict__ dinv,
                            const float* __restrict__ b, int n) {
    int total = n * F_HID;
    int stride = gridDim.x * blockDim.x;
    for (int i = blockIdx.x * blockDim.x + threadIdx.x; i < total; i += stride) {
        int nd = i >> 6;
        int j = i & 63;
        float v = fmaf(agg[i], dinv[nd], b[j]);
        agg[i] = v > 0.f ? v : 0.f;
    }
}

// ---------------- layer 2 linear: h2s = dinv * (z1 @ W2); agg2 = h2s ----------------
// block = 256 = 4 waves, one wave per node, lanes 0..39 active.
__global__ void k_lin2(const float* __restrict__ z, const float* __restrict__ W2,
                       const float* __restrict__ dinv,
                       float* __restrict__ h2s, float* __restrict__ agg2, int n) {
    __shared__ float Ws[F_HID * F_OUT];  // 10 KB
    int t = threadIdx.x;
    for (int i = t; i < F_HID * F_OUT; i += 256) Ws[i] = W2[i];
    __syncthreads();
    int lane = t & 63;
    int nd = blockIdx.x * 4 + (t >> 6);
    if (nd >= n) return;
    float acc = 0.f;
    if (lane < F_OUT) {
#pragma unroll 8
        for (int k = 0; k < F_HID; ++k)
            acc = fmaf(z[nd * F_HID + k], Ws[k * F_OUT + lane], acc);
        float v = acc * dinv[nd];
        h2s[nd * F_OUT + lane] = v;
        agg2[nd * F_OUT + lane] = v;   // self-loop pre-seeded
    }
}

// ---------------- edge aggregation, 40 features ----------------
__global__ void k_agg40(const int* __restrict__ row, const int* __restrict__ col,
                        const float* __restrict__ h, float* __restrict__ agg, int E) {
    int gtid = blockIdx.x * blockDim.x + threadIdx.x;
    int wid = gtid >> 6;
    int lane = threadIdx.x & 63;
    int nwaves = (gridDim.x * blockDim.x) >> 6;
    for (int e = wid; e < E; e += nwaves) {
        int r = row[e];
        int c = col[e];
        if (lane < F_OUT) {
            float v = h[r * F_OUT + lane];
            atomicAdd(&agg[c * F_OUT + lane], v);
        }
    }
}

// ---------------- out = log_softmax(dinv[c]*agg2 + b2) ----------------
__global__ void k_logsm(const float* __restrict__ agg2, const float* __restrict__ dinv,
                        const float* __restrict__ b2, float* __restrict__ out, int n) {
    int t = threadIdx.x;
    int lane = t & 63;
    int nd = blockIdx.x * 4 + (t >> 6);
    if (nd >= n) return;
    float v = (lane < F_OUT) ? fmaf(agg2[nd * F_OUT + lane], dinv[nd], b2[lane]) : -1e30f;
    float m = v;
#pragma unroll
    for (int off = 32; off > 0; off >>= 1) m = fmaxf(m, __shfl_xor(m, off));
    float ex = (lane < F_OUT) ? expf(v - m) : 0.f;
    float s = ex;
#pragma unroll
    for (int off = 32; off > 0; off >>= 1) s += __shfl_xor(s, off);
    if (lane < F_OUT) out[nd * F_OUT + lane] = v - m - logf(s);
}

extern "C" void kernel_launch(void* const* d_in, const int* in_sizes, int n_in,
                              void* d_out, int out_size, void* d_ws, size_t ws_size,
                              hipStream_t stream) {
    const float* x    = (const float*)d_in[0];
    const int*   ei   = (const int*)d_in[1];   // [2, E] flat: row = ei[0:E], col = ei[E:2E]
    const float* W1   = (const float*)d_in[2];
    const float* b1   = (const float*)d_in[3];
    const float* W2   = (const float*)d_in[4];
    const float* b2   = (const float*)d_in[5];
    float* out = (float*)d_out;

    const int n = in_sizes[0] / F_IN;
    const int E = in_sizes[1] / 2;
    const int* row = ei;
    const int* col = ei + E;

    // workspace layout (floats)
    float* ws = (float*)d_ws;
    float* dinv = ws;                         // n (used as deg first)
    float* h1s  = ws + 102400;                // n*64
    float* agg1 = h1s + (size_t)n * F_HID;    // n*64   (becomes z1 in place)
    float* h2s  = agg1 + (size_t)n * F_HID;   // n*40
    float* agg2 = h2s + (size_t)n * F_OUT;    // n*40

    // degree + dinv
    k_init_deg<<<(n + 255) / 256, 256, 0, stream>>>(dinv, n);
    k_count_deg<<<2048, 256, 0, stream>>>(col, E, dinv);
    k_dinv<<<(n + 255) / 256, 256, 0, stream>>>(dinv, n);

    // layer 1
    k_lin1<<<(n + 7) / 8, 256, 0, stream>>>(x, W1, dinv, h1s, agg1, n);
    k_agg64<<<2048, 256, 0, stream>>>(row, col, h1s, agg1, E);
    k_bias_relu<<<2048, 256, 0, stream>>>(agg1, dinv, b1, n);

    // layer 2
    k_lin2<<<(n + 3) / 4, 256, 0, stream>>>(agg1, W2, dinv, h2s, agg2, n);
    k_agg40<<<2048, 256, 0, stream>>>(row, col, h2s, agg2, E);
    k_logsm<<<(n + 3) / 4, 256, 0, stream>>>(agg2, dinv, b2, out, n);
}

// Round 2
// 777.758 us; speedup vs baseline: 1.9546x; 1.9546x over previous
//
#include <hip/hip_runtime.h>

#define F_IN  128
#define F_HID 64
#define F_OUT 40
#define SCAN_CHUNK 2048

// ---------------- CSR build: histogram of destinations ----------------
__global__ void k_hist(const int* __restrict__ col, int E, int* __restrict__ counts) {
    int i = blockIdx.x * blockDim.x + threadIdx.x;
    int stride = gridDim.x * blockDim.x;
    for (int e = i; e < E; e += stride)
        atomicAdd(&counts[col[e]], 1);
}

// per-chunk sums
__global__ void k_scan_partial(const int* __restrict__ counts, int* __restrict__ partial, int n) {
    __shared__ int lds[256];
    int base = blockIdx.x * SCAN_CHUNK;
    int s = 0;
    for (int i = threadIdx.x; i < SCAN_CHUNK; i += 256) {
        int idx = base + i;
        s += (idx < n) ? counts[idx] : 0;
    }
    lds[threadIdx.x] = s;
    __syncthreads();
    for (int off = 128; off > 0; off >>= 1) {
        if (threadIdx.x < off) lds[threadIdx.x] += lds[threadIdx.x + off];
        __syncthreads();
    }
    if (threadIdx.x == 0) partial[blockIdx.x] = lds[0];
}

// exclusive scan of the (<=1024) partials, single block
__global__ void k_scan_spine(int* __restrict__ partial, int nb) {
    __shared__ int lds[1024];
    int t = threadIdx.x;
    for (int i = t; i < nb; i += 256) lds[i] = partial[i];
    __syncthreads();
    if (t == 0) {
        int run = 0;
        for (int i = 0; i < nb; ++i) { int v = lds[i]; lds[i] = run; run += v; }
    }
    __syncthreads();
    for (int i = t; i < nb; i += 256) partial[i] = lds[i];
}

// final exclusive scan: counts -> offs
__global__ void k_scan_final(const int* __restrict__ counts, const int* __restrict__ partial,
                             int* __restrict__ offs, int n, int E) {
    __shared__ int lds[256];
    int t = threadIdx.x;
    int idx0 = blockIdx.x * SCAN_CHUNK + t * 8;
    int vals[8];
    int s = 0;
#pragma unroll
    for (int k = 0; k < 8; ++k) {
        int idx = idx0 + k;
        vals[k] = (idx < n) ? counts[idx] : 0;
        s += vals[k];
    }
    lds[t] = s;
    __syncthreads();
    // in-place Hillis-Steele inclusive scan
    for (int off = 1; off < 256; off <<= 1) {
        int v = (t >= off) ? lds[t - off] : 0;
        __syncthreads();
        lds[t] += v;
        __syncthreads();
    }
    int run = partial[blockIdx.x] + lds[t] - s;   // exclusive base for this thread
#pragma unroll
    for (int k = 0; k < 8; ++k) {
        int idx = idx0 + k;
        if (idx < n) offs[idx] = run;
        run += vals[k];
    }
    if (blockIdx.x == 0 && t == 0) offs[n] = E;
}

// dinv = rsqrt(deg), cursor = offs  (fused)
__global__ void k_finalize(const int* __restrict__ counts, const int* __restrict__ offs,
                           float* __restrict__ dinv, int* __restrict__ cursor, int n) {
    int i = blockIdx.x * blockDim.x + threadIdx.x;
    if (i < n) {
        dinv[i] = rsqrtf((float)counts[i] + 1.0f);  // +1 self-loop
        cursor[i] = offs[i];
    }
}

// scatter source indices into CSR order
__global__ void k_scatter(const int* __restrict__ row, const int* __restrict__ col,
                          int* __restrict__ cursor, int* __restrict__ srow, int E) {
    int i = blockIdx.x * blockDim.x + threadIdx.x;
    int stride = gridDim.x * blockDim.x;
    for (int e = i; e < E; e += stride) {
        int p = atomicAdd(&cursor[col[e]], 1);
        srow[p] = row[e];
    }
}

// ---------------- layer 1 linear: h1s = dinv * (x @ W1) ----------------
__global__ void k_lin1(const float* __restrict__ x, const float* __restrict__ W1,
                       const float* __restrict__ dinv,
                       float* __restrict__ h1s, int n) {
    __shared__ float Ws[F_IN * F_HID];   // 32 KB
    __shared__ float xs[8][F_IN];        // 4 KB
    int t = threadIdx.x;
    for (int i = t; i < F_IN * F_HID; i += 256) Ws[i] = W1[i];
    int node0 = blockIdx.x * 8;
    for (int i = t; i < 8 * F_IN; i += 256) {
        int nd = node0 + (i >> 7);
        xs[i >> 7][i & 127] = (nd < n) ? x[nd * F_IN + (i & 127)] : 0.f;
    }
    __syncthreads();
    int local = t >> 5;
    int j0 = t & 31;
    float acc0 = 0.f, acc1 = 0.f;
#pragma unroll 8
    for (int k = 0; k < F_IN; ++k) {
        float xv = xs[local][k];
        acc0 = fmaf(xv, Ws[k * F_HID + j0], acc0);
        acc1 = fmaf(xv, Ws[k * F_HID + j0 + 32], acc1);
    }
    int nd = node0 + local;
    if (nd < n) {
        float s = dinv[nd];
        h1s[nd * F_HID + j0]      = acc0 * s;
        h1s[nd * F_HID + j0 + 32] = acc1 * s;
    }
}

// ---------------- layer-1 CSR aggregation + bias + relu, wave per node ----------------
__global__ void k_agg1_csr(const float* __restrict__ h1s, const int* __restrict__ offs,
                           const int* __restrict__ srow, const float* __restrict__ dinv,
                           const float* __restrict__ b1, float* __restrict__ z1, int n) {
    int lane = threadIdx.x & 63;
    int node = blockIdx.x * (blockDim.x >> 6) + (threadIdx.x >> 6);
    if (node >= n) return;
    int beg = offs[node], end = offs[node + 1];
    float acc = h1s[node * F_HID + lane];   // self-loop
    for (int base = beg; base < end; base += 64) {
        int cnt = min(64, end - base);
        int r = (base + lane < end) ? srow[base + lane] : 0;
        int j = 0;
        for (; j + 4 <= cnt; j += 4) {
            int r0 = __shfl(r, j), r1 = __shfl(r, j + 1);
            int r2 = __shfl(r, j + 2), r3 = __shfl(r, j + 3);
            float v0 = h1s[r0 * F_HID + lane];
            float v1 = h1s[r1 * F_HID + lane];
            float v2 = h1s[r2 * F_HID + lane];
            float v3 = h1s[r3 * F_HID + lane];
            acc += v0 + v1 + v2 + v3;
        }
        for (; j < cnt; ++j) {
            int rj = __shfl(r, j);
            acc += h1s[rj * F_HID + lane];
        }
    }
    float v = fmaf(acc, dinv[node], b1[lane]);
    z1[node * F_HID + lane] = v > 0.f ? v : 0.f;
}

// ---------------- layer 2 linear: h2s = dinv * (z1 @ W2) ----------------
__global__ void k_lin2(const float* __restrict__ z, const float* __restrict__ W2,
                       const float* __restrict__ dinv,
                       float* __restrict__ h2s, int n) {
    __shared__ float Ws[F_HID * F_OUT];
    int t = threadIdx.x;
    for (int i = t; i < F_HID * F_OUT; i += 256) Ws[i] = W2[i];
    __syncthreads();
    int lane = t & 63;
    int nd = blockIdx.x * 4 + (t >> 6);
    if (nd >= n) return;
    if (lane < F_OUT) {
        float acc = 0.f;
#pragma unroll 8
        for (int k = 0; k < F_HID; ++k)
            acc = fmaf(z[nd * F_HID + k], Ws[k * F_OUT + lane], acc);
        h2s[nd * F_OUT + lane] = acc * dinv[nd];
    }
}

// ---------------- layer-2 CSR aggregation + bias + log_softmax, wave per node ----------------
__global__ void k_agg2_csr(const float* __restrict__ h2s, const int* __restrict__ offs,
                           const int* __restrict__ srow, const float* __restrict__ dinv,
                           const float* __restrict__ b2, float* __restrict__ out, int n) {
    int lane = threadIdx.x & 63;
    int node = blockIdx.x * (blockDim.x >> 6) + (threadIdx.x >> 6);
    if (node >= n) return;
    int beg = offs[node], end = offs[node + 1];
    float acc = (lane < F_OUT) ? h2s[node * F_OUT + lane] : 0.f;  // self-loop
    for (int base = beg; base < end; base += 64) {
        int cnt = min(64, end - base);
        int r = (base + lane < end) ? srow[base + lane] : 0;
        int j = 0;
        for (; j + 4 <= cnt; j += 4) {
            int r0 = __shfl(r, j), r1 = __shfl(r, j + 1);
            int r2 = __shfl(r, j + 2), r3 = __shfl(r, j + 3);
            if (lane < F_OUT)
                acc += h2s[r0 * F_OUT + lane] + h2s[r1 * F_OUT + lane]
                     + h2s[r2 * F_OUT + lane] + h2s[r3 * F_OUT + lane];
        }
        for (; j < cnt; ++j) {
            int rj = __shfl(r, j);
            if (lane < F_OUT) acc += h2s[rj * F_OUT + lane];
        }
    }
    float v = (lane < F_OUT) ? fmaf(acc, dinv[node], b2[lane]) : -1e30f;
    float m = v;
#pragma unroll
    for (int off = 32; off > 0; off >>= 1) m = fmaxf(m, __shfl_xor(m, off));
    float ex = (lane < F_OUT) ? expf(v - m) : 0.f;
    float s = ex;
#pragma unroll
    for (int off = 32; off > 0; off >>= 1) s += __shfl_xor(s, off);
    if (lane < F_OUT) out[node * F_OUT + lane] = v - m - logf(s);
}

extern "C" void kernel_launch(void* const* d_in, const int* in_sizes, int n_in,
                              void* d_out, int out_size, void* d_ws, size_t ws_size,
                              hipStream_t stream) {
    const float* x  = (const float*)d_in[0];
    const int*   ei = (const int*)d_in[1];
    const float* W1 = (const float*)d_in[2];
    const float* b1 = (const float*)d_in[3];
    const float* W2 = (const float*)d_in[4];
    const float* b2 = (const float*)d_in[5];
    float* out = (float*)d_out;

    const int n = in_sizes[0] / F_IN;
    const int E = in_sizes[1] / 2;
    const int* row = ei;
    const int* col = ei + E;

    // workspace layout
    char* p = (char*)d_ws;
    float* dinv   = (float*)p;               p += (size_t)n * 4;
    float* h1s    = (float*)p;               p += (size_t)n * F_HID * 4;
    float* z1     = (float*)p;               p += (size_t)n * F_HID * 4;
    float* h2s    = (float*)p;               p += (size_t)n * F_OUT * 4;
    int*   counts = (int*)p;                 p += (size_t)n * 4;
    int*   offs   = (int*)p;                 p += (size_t)(n + 1) * 4;
    int*   cursor = (int*)p;                 p += (size_t)n * 4;
    int*   partial= (int*)p;                 p += 1024 * 4;
    int*   srow   = (int*)p;                 p += (size_t)E * 4;

    const int nScanBlocks = (n + SCAN_CHUNK - 1) / SCAN_CHUNK;

    // --- CSR build ---
    hipMemsetAsync(counts, 0, (size_t)n * 4, stream);
    k_hist<<<2048, 256, 0, stream>>>(col, E, counts);
    k_scan_partial<<<nScanBlocks, 256, 0, stream>>>(counts, partial, n);
    k_scan_spine<<<1, 256, 0, stream>>>(partial, nScanBlocks);
    k_scan_final<<<nScanBlocks, 256, 0, stream>>>(counts, partial, offs, n, E);
    k_finalize<<<(n + 255) / 256, 256, 0, stream>>>(counts, offs, dinv, cursor, n);
    k_scatter<<<2048, 256, 0, stream>>>(row, col, cursor, srow, E);

    // --- layer 1 ---
    k_lin1<<<(n + 7) / 8, 256, 0, stream>>>(x, W1, dinv, h1s, n);
    k_agg1_csr<<<(n + 3) / 4, 256, 0, stream>>>(h1s, offs, srow, dinv, b1, z1, n);

    // --- layer 2 ---
    k_lin2<<<(n + 3) / 4, 256, 0, stream>>>(z1, W2, dinv, h2s, n);
    k_agg2_csr<<<(n + 3) / 4, 256, 0, stream>>>(h2s, offs, srow, dinv, b2, out, n);
}